// Round 1
// baseline (736.776 us; speedup 1.0000x reference)
//
#include <hip/hip_runtime.h>
#include <math.h>

#define BATCH   2
#define TLEN    1024
#define DMODEL  1024
#define DINNER  2048
#define DSTATE  16
#define DTRANK  64
#define NPROJ   (DTRANK + 2*DSTATE)   // 96
#define CH      64
#define NCH     (TLEN / CH)           // 16

__device__ __forceinline__ float siluf(float u) {
    return u / (1.0f + __expf(-u));
}
__device__ __forceinline__ float softplusf(float x) {
    return (x > 20.0f) ? x : log1pf(__expf(x));
}

// ---------------------------------------------------------------------------
// Generic fp32 tiled GEMM: C[M,N] = A[M,K] @ B[K,N]  (row-major, strided)
// BM=BN=64, BK=16, 256 threads, 4x4 per thread. M must be multiple of 64
// (grid.y covers M). N guarded (must be multiple of 4). K multiple of 16.
// EPI=1: C = softplus(C + bias[col])
// ---------------------------------------------------------------------------
template<int EPI>
__global__ __launch_bounds__(256)
void gemm_f32(const float* __restrict__ A, int lda,
              const float* __restrict__ B, int ldb,
              float* __restrict__ C, int ldc,
              int N, int K,
              const float* __restrict__ bias)
{
    __shared__ float As[16][64 + 4];
    __shared__ float Bs[16][64 + 4];
    const int tid  = threadIdx.x;
    const int brow = blockIdx.y * 64;
    const int bcol = blockIdx.x * 64;
    const int tr = ((tid >> 4) & 15) << 2;   // 0..60
    const int tc = (tid & 15) << 2;          // 0..60
    const int ar = tid >> 2;                 // 0..63
    const int ac = (tid & 3) << 2;           // 0,4,8,12
    const int br = tid >> 4;                 // 0..15
    const int bc = (tid & 15) << 2;          // 0..60

    float acc[4][4] = {{0.f,0.f,0.f,0.f},{0.f,0.f,0.f,0.f},
                       {0.f,0.f,0.f,0.f},{0.f,0.f,0.f,0.f}};

    for (int k0 = 0; k0 < K; k0 += 16) {
        float4 av = *(const float4*)(A + (size_t)(brow + ar) * lda + k0 + ac);
        As[ac+0][ar] = av.x; As[ac+1][ar] = av.y;
        As[ac+2][ar] = av.z; As[ac+3][ar] = av.w;

        float4 bv = make_float4(0.f, 0.f, 0.f, 0.f);
        if (bcol + bc < N)
            bv = *(const float4*)(B + (size_t)(k0 + br) * ldb + bcol + bc);
        *(float4*)&Bs[br][bc] = bv;

        __syncthreads();
        #pragma unroll
        for (int k = 0; k < 16; ++k) {
            float4 a4 = *(const float4*)&As[k][tr];
            float4 b4 = *(const float4*)&Bs[k][tc];
            float am[4] = {a4.x, a4.y, a4.z, a4.w};
            float bn[4] = {b4.x, b4.y, b4.z, b4.w};
            #pragma unroll
            for (int m = 0; m < 4; ++m)
                #pragma unroll
                for (int n = 0; n < 4; ++n)
                    acc[m][n] = fmaf(am[m], bn[n], acc[m][n]);
        }
        __syncthreads();
    }

    #pragma unroll
    for (int m = 0; m < 4; ++m) {
        const int gr = brow + tr + m;
        #pragma unroll
        for (int n = 0; n < 4; ++n) {
            const int gc = bcol + tc + n;
            if (gc < N) {
                float v = acc[m][n];
                if (EPI == 1) v = softplusf(v + bias[gc]);
                C[(size_t)gr * ldc + gc] = v;
            }
        }
    }
}

// ---------------------------------------------------------------------------
// Depthwise causal conv (D_CONV=4) + bias + SiLU over x_b (first half of xz)
// ---------------------------------------------------------------------------
__global__ __launch_bounds__(256)
void conv_silu(const float* __restrict__ xz, const float* __restrict__ conv_w,
               const float* __restrict__ conv_b, float* __restrict__ xc)
{
    const int idx = blockIdx.x * 256 + threadIdx.x;   // over B*T*DINNER = 2^22
    const int d = idx & (DINNER - 1);
    const int t = (idx >> 11) & (TLEN - 1);
    const int b = idx >> 21;

    const float* xb = xz + (size_t)b * TLEN * (2*DINNER) + d;
    float s = conv_b[d];
    const float4 w = *(const float4*)(conv_w + d * 4);
    const float wk[4] = {w.x, w.y, w.z, w.w};
    #pragma unroll
    for (int k = 0; k < 4; ++k) {
        const int tt = t + k - 3;
        if (tt >= 0) s = fmaf(xb[(size_t)tt * (2*DINNER)], wk[k], s);
    }
    xc[idx] = siluf(s);
}

// ---------------------------------------------------------------------------
// Scan pass A: per (b, chunk, d) — local scan from h0=0 and sum of delta
// ---------------------------------------------------------------------------
__global__ __launch_bounds__(256)
void scan1(const float* __restrict__ delta, const float* __restrict__ xc,
           const float* __restrict__ proj, const float* __restrict__ A_log,
           float* __restrict__ hloc, float* __restrict__ sumdel)
{
    const int idx = blockIdx.x * 256 + threadIdx.x;   // over B*NCH*DINNER = 2^16
    const int d = idx & (DINNER - 1);
    const int c = (idx >> 11) & (NCH - 1);
    const int b = idx >> 15;

    float Aa[DSTATE];
    #pragma unroll
    for (int s = 0; s < DSTATE; ++s) Aa[s] = -__expf(A_log[d * DSTATE + s]);

    float h[DSTATE];
    #pragma unroll
    for (int s = 0; s < DSTATE; ++s) h[s] = 0.f;
    float sd = 0.f;

    const int t0 = c * CH;
    const float* dptr = delta + ((size_t)(b * TLEN + t0)) * DINNER + d;
    const float* xptr = xc    + ((size_t)(b * TLEN + t0)) * DINNER + d;
    const float* pptr = proj  + ((size_t)(b * TLEN + t0)) * NPROJ;

    for (int t = 0; t < CH; ++t) {
        const float dl = dptr[(size_t)t * DINNER];
        const float xv = xptr[(size_t)t * DINNER];
        const float dx = dl * xv;
        sd += dl;
        #pragma unroll
        for (int s = 0; s < DSTATE; ++s) {
            const float ab = __expf(dl * Aa[s]);
            const float Bv = pptr[t * NPROJ + DTRANK + s];
            h[s] = fmaf(ab, h[s], dx * Bv);
        }
    }
    const size_t base = (((size_t)(b * DINNER + d)) * NCH + c) * DSTATE;
    #pragma unroll
    for (int s = 0; s < DSTATE; ++s) hloc[base + s] = h[s];
    sumdel[(size_t)(b * DINNER + d) * NCH + c] = sd;
}

// ---------------------------------------------------------------------------
// Scan pass B: per (b,d) — sequential combine of chunk states
// ---------------------------------------------------------------------------
__global__ __launch_bounds__(256)
void scan_combine(const float* __restrict__ hloc, const float* __restrict__ sumdel,
                  const float* __restrict__ A_log, float* __restrict__ hstart)
{
    const int idx = blockIdx.x * 256 + threadIdx.x;   // over B*DINNER = 4096
    const int d = idx & (DINNER - 1);

    float Aa[DSTATE];
    #pragma unroll
    for (int s = 0; s < DSTATE; ++s) Aa[s] = -__expf(A_log[d * DSTATE + s]);

    float h[DSTATE];
    #pragma unroll
    for (int s = 0; s < DSTATE; ++s) h[s] = 0.f;

    const size_t base = (size_t)idx * NCH * DSTATE;
    for (int c = 0; c < NCH; ++c) {
        #pragma unroll
        for (int s = 0; s < DSTATE; ++s) hstart[base + c * DSTATE + s] = h[s];
        const float sd = sumdel[(size_t)idx * NCH + c];
        #pragma unroll
        for (int s = 0; s < DSTATE; ++s)
            h[s] = fmaf(__expf(Aa[s] * sd), h[s], hloc[base + c * DSTATE + s]);
    }
}

// ---------------------------------------------------------------------------
// Scan pass C: recompute with correct h0, produce y = (h.C + D*xc) * silu(z)
// ---------------------------------------------------------------------------
__global__ __launch_bounds__(256)
void scan2(const float* __restrict__ delta, const float* __restrict__ xc,
           const float* __restrict__ proj, const float* __restrict__ A_log,
           const float* __restrict__ D_param, const float* __restrict__ xz,
           const float* __restrict__ hstart, float* __restrict__ y)
{
    const int idx = blockIdx.x * 256 + threadIdx.x;   // over B*NCH*DINNER
    const int d = idx & (DINNER - 1);
    const int c = (idx >> 11) & (NCH - 1);
    const int b = idx >> 15;

    float Aa[DSTATE];
    #pragma unroll
    for (int s = 0; s < DSTATE; ++s) Aa[s] = -__expf(A_log[d * DSTATE + s]);

    float h[DSTATE];
    const size_t hbase = (((size_t)(b * DINNER + d)) * NCH + c) * DSTATE;
    #pragma unroll
    for (int s = 0; s < DSTATE; ++s) h[s] = hstart[hbase + s];

    const float Dp = D_param[d];
    const int t0 = c * CH;
    const float* dptr = delta + ((size_t)(b * TLEN + t0)) * DINNER + d;
    const float* xptr = xc    + ((size_t)(b * TLEN + t0)) * DINNER + d;
    const float* pptr = proj  + ((size_t)(b * TLEN + t0)) * NPROJ;
    const float* zptr = xz + ((size_t)(b * TLEN + t0)) * (2*DINNER) + DINNER + d;
    float* yptr = y + ((size_t)(b * TLEN + t0)) * DINNER + d;

    for (int t = 0; t < CH; ++t) {
        const float dl = dptr[(size_t)t * DINNER];
        const float xv = xptr[(size_t)t * DINNER];
        const float dx = dl * xv;
        float yt = 0.f;
        #pragma unroll
        for (int s = 0; s < DSTATE; ++s) {
            const float ab = __expf(dl * Aa[s]);
            const float Bv = pptr[t * NPROJ + DTRANK + s];
            h[s] = fmaf(ab, h[s], dx * Bv);
            const float Cv = pptr[t * NPROJ + DTRANK + DSTATE + s];
            yt = fmaf(h[s], Cv, yt);
        }
        yt = fmaf(Dp, xv, yt);
        const float z = zptr[(size_t)t * (2*DINNER)];
        yptr[(size_t)t * DINNER] = yt * siluf(z);
    }
}

// ---------------------------------------------------------------------------
extern "C" void kernel_launch(void* const* d_in, const int* in_sizes, int n_in,
                              void* d_out, int out_size, void* d_ws, size_t ws_size,
                              hipStream_t stream)
{
    const float* x      = (const float*)d_in[0];
    const float* W_in   = (const float*)d_in[1];
    const float* conv_w = (const float*)d_in[2];
    const float* conv_b = (const float*)d_in[3];
    const float* W_xproj= (const float*)d_in[4];
    const float* W_dt   = (const float*)d_in[5];
    const float* b_dt   = (const float*)d_in[6];
    const float* A_log  = (const float*)d_in[7];
    const float* D_param= (const float*)d_in[8];
    const float* W_out  = (const float*)d_in[9];
    float* out = (float*)d_out;

    float* ws = (float*)d_ws;
    float* xz     = ws;                     // 2*1024*4096   = 8388608
    float* xc     = xz     + 8388608;       // 2*1024*2048   = 4194304
    float* proj   = xc     + 4194304;       // 2*1024*96     = 196608
    float* delta  = proj   + 196608;        // 2*1024*2048   = 4194304
    float* yb     = delta  + 4194304;       // 2*1024*2048   = 4194304
    float* hloc   = yb     + 4194304;       // 2*2048*16*16  = 1048576
    float* sumdel = hloc   + 1048576;       // 2*2048*16     = 65536
    float* hstart = sumdel + 65536;         // 2*2048*16*16  = 1048576

    dim3 blk(256);

    // 1. xz = x @ W_in              M=2048, N=4096, K=1024
    gemm_f32<0><<<dim3(4096/64, 2048/64), blk, 0, stream>>>(
        x, DMODEL, W_in, 2*DINNER, xz, 2*DINNER, 2*DINNER, DMODEL, nullptr);

    // 2. xc = silu(conv(x_b))
    conv_silu<<<(BATCH*TLEN*DINNER)/256, blk, 0, stream>>>(xz, conv_w, conv_b, xc);

    // 3. proj = xc @ W_xproj        M=2048, N=96, K=2048
    gemm_f32<0><<<dim3(2, 2048/64), blk, 0, stream>>>(
        xc, DINNER, W_xproj, NPROJ, proj, NPROJ, NPROJ, DINNER, nullptr);

    // 4. delta = softplus(proj[:, :64] @ W_dt + b_dt)   M=2048, N=2048, K=64
    gemm_f32<1><<<dim3(2048/64, 2048/64), blk, 0, stream>>>(
        proj, NPROJ, W_dt, DINNER, delta, DINNER, DINNER, DTRANK, b_dt);

    // 5-7. chunked scan
    scan1<<<65536/256, blk, 0, stream>>>(delta, xc, proj, A_log, hloc, sumdel);
    scan_combine<<<4096/256, blk, 0, stream>>>(hloc, sumdel, A_log, hstart);
    scan2<<<65536/256, blk, 0, stream>>>(delta, xc, proj, A_log, D_param, xz, hstart, yb);

    // 8. out = yb @ W_out           M=2048, N=1024, K=2048
    gemm_f32<0><<<dim3(1024/64, 2048/64), blk, 0, stream>>>(
        yb, DINNER, W_out, DMODEL, out, DMODEL, DMODEL, DINNER, nullptr);
}

// Round 2
// 348.757 us; speedup vs baseline: 2.1126x; 2.1126x over previous
//
#include <hip/hip_runtime.h>
#include <math.h>

#define BATCH   2
#define TLEN    1024
#define DMODEL  1024
#define DINNER  2048
#define DSTATE  16
#define DTRANK  64
#define NPROJ   (DTRANK + 2*DSTATE)   // 96
#define CH      64
#define NCH     (TLEN / CH)           // 16

typedef __attribute__((ext_vector_type(8))) short short8;
typedef __attribute__((ext_vector_type(4))) float f32x4;

__device__ __forceinline__ float siluf(float u) {
    return u / (1.0f + __expf(-u));
}
__device__ __forceinline__ float softplusf(float x) {
    return (x > 20.0f) ? x : log1pf(__expf(x));
}
__device__ __forceinline__ unsigned short f2bf(float f) {
    union { float f; unsigned u; } v; v.f = f;
    unsigned r = v.u + 0x7FFF + ((v.u >> 16) & 1);   // round-to-nearest-even
    return (unsigned short)(r >> 16);
}

#define GLOAD_LDS16(g, l) \
  __builtin_amdgcn_global_load_lds( \
     (const __attribute__((address_space(1))) unsigned int*)(g), \
     (__attribute__((address_space(3))) unsigned int*)(l), 16, 0, 0)

// ---------------------------------------------------------------------------
// bf16 MFMA GEMM: C[M, N] fp32 = A[M,K]bf16 @ BT[N,K]bf16^T
// BM=128, BN=NFRAG*32 (4->128, 2->64), BK=32, 256 threads = 4 waves (2x2).
// m97 structure: global_load_lds width-16 staging, 2 barriers per K-step.
// M,N multiples of tile; K multiple of 32.
// ---------------------------------------------------------------------------
template<int NFRAG>
__global__ __launch_bounds__(256)
void gemm_bf16(const unsigned short* __restrict__ A,
               const unsigned short* __restrict__ BT,
               float* __restrict__ C, int ldc, int K)
{
    constexpr int BN = NFRAG * 32;
    __shared__ unsigned short As[128 * 32];
    __shared__ unsigned short Bs[BN * 32];

    const int tid  = threadIdx.x;
    const int wid  = tid >> 6;
    const int lane = tid & 63;
    const int brow = blockIdx.y * 128;
    const int bcol = blockIdx.x * BN;
    const int wr = (wid >> 1) * 64;           // wave row offset in tile
    const int wc = (wid & 1) * (NFRAG * 16);  // wave col offset in tile
    const int lrow = lane & 15;
    const int lk   = (lane >> 4) * 8;

    f32x4 acc[4][NFRAG] = {};

    for (int k0 = 0; k0 < K; k0 += 32) {
        // stage A tile [128][32] bf16 = 8KB: 512 16B-chunks, chunk c -> (row=c>>2, k=(c&3)*8)
        #pragma unroll
        for (int it = 0; it < 2; ++it) {
            const int c = it * 256 + tid;
            const unsigned short* g = A + (size_t)(brow + (c >> 2)) * K + k0 + (c & 3) * 8;
            GLOAD_LDS16(g, As + (size_t)(it * 256 + wid * 64) * 8);
        }
        // stage B tile [BN][32]
        #pragma unroll
        for (int it = 0; it < BN / 64; ++it) {
            const int c = it * 256 + tid;
            const unsigned short* g = BT + (size_t)(bcol + (c >> 2)) * K + k0 + (c & 3) * 8;
            GLOAD_LDS16(g, Bs + (size_t)(it * 256 + wid * 64) * 8);
        }
        __syncthreads();   // drains vmcnt (global_load_lds) per gfx950 semantics

        short8 af[4], bfr[NFRAG];
        #pragma unroll
        for (int m = 0; m < 4; ++m)
            af[m] = *(const short8*)(As + (size_t)(wr + m * 16 + lrow) * 32 + lk);
        #pragma unroll
        for (int n = 0; n < NFRAG; ++n)
            bfr[n] = *(const short8*)(Bs + (size_t)(wc + n * 16 + lrow) * 32 + lk);

        #pragma unroll
        for (int m = 0; m < 4; ++m)
            #pragma unroll
            for (int n = 0; n < NFRAG; ++n)
                acc[m][n] = __builtin_amdgcn_mfma_f32_16x16x32_bf16(af[m], bfr[n], acc[m][n], 0, 0, 0);
        __syncthreads();
    }

    // C/D layout (m89-verified): col = lane&15, row = (lane>>4)*4 + r
    const int crow = (lane >> 4) * 4;
    #pragma unroll
    for (int m = 0; m < 4; ++m)
        #pragma unroll
        for (int n = 0; n < NFRAG; ++n) {
            float* cp = C + (size_t)(brow + wr + m * 16 + crow) * ldc + bcol + wc + n * 16 + lrow;
            #pragma unroll
            for (int r = 0; r < 4; ++r)
                cp[(size_t)r * ldc] = acc[m][n][r];
        }
}

// ---------------------------------------------------------------------------
// fp32 tiled GEMM (kept for the small/sensitive GEMMs). Split-K via gridDim.z:
// each z-slice covers kchunk of K and writes C + z*zstride.
// EPI=1: C = softplus(C + bias[col])
// ---------------------------------------------------------------------------
template<int EPI>
__global__ __launch_bounds__(256)
void gemm_f32(const float* __restrict__ A, int lda,
              const float* __restrict__ B, int ldb,
              float* __restrict__ C, int ldc,
              int N, int kchunk,
              const float* __restrict__ bias, size_t zstride)
{
    __shared__ float As[16][64 + 4];
    __shared__ float Bs[16][64 + 4];
    const int tid  = threadIdx.x;
    const int brow = blockIdx.y * 64;
    const int bcol = blockIdx.x * 64;
    const int kbeg = blockIdx.z * kchunk;
    C += (size_t)blockIdx.z * zstride;
    const int tr = ((tid >> 4) & 15) << 2;
    const int tc = (tid & 15) << 2;
    const int ar = tid >> 2;
    const int ac = (tid & 3) << 2;
    const int br = tid >> 4;
    const int bc = (tid & 15) << 2;

    float acc[4][4] = {{0.f,0.f,0.f,0.f},{0.f,0.f,0.f,0.f},
                       {0.f,0.f,0.f,0.f},{0.f,0.f,0.f,0.f}};

    for (int k0 = kbeg; k0 < kbeg + kchunk; k0 += 16) {
        float4 av = *(const float4*)(A + (size_t)(brow + ar) * lda + k0 + ac);
        As[ac+0][ar] = av.x; As[ac+1][ar] = av.y;
        As[ac+2][ar] = av.z; As[ac+3][ar] = av.w;

        float4 bv = make_float4(0.f, 0.f, 0.f, 0.f);
        if (bcol + bc < N)
            bv = *(const float4*)(B + (size_t)(k0 + br) * ldb + bcol + bc);
        *(float4*)&Bs[br][bc] = bv;

        __syncthreads();
        #pragma unroll
        for (int k = 0; k < 16; ++k) {
            float4 a4 = *(const float4*)&As[k][tr];
            float4 b4 = *(const float4*)&Bs[k][tc];
            float am[4] = {a4.x, a4.y, a4.z, a4.w};
            float bn[4] = {b4.x, b4.y, b4.z, b4.w};
            #pragma unroll
            for (int m = 0; m < 4; ++m)
                #pragma unroll
                for (int n = 0; n < 4; ++n)
                    acc[m][n] = fmaf(am[m], bn[n], acc[m][n]);
        }
        __syncthreads();
    }

    #pragma unroll
    for (int m = 0; m < 4; ++m) {
        const int gr = brow + tr + m;
        #pragma unroll
        for (int n = 0; n < 4; ++n) {
            const int gc = bcol + tc + n;
            if (gc < N) {
                float v = acc[m][n];
                if (EPI == 1) v = softplusf(v + bias[gc]);
                C[(size_t)gr * ldc + gc] = v;
            }
        }
    }
}

// reduce 8 split-K partials
__global__ __launch_bounds__(256)
void reduce8(const float* __restrict__ in, float* __restrict__ out, int n, size_t zstride)
{
    const int i = blockIdx.x * 256 + threadIdx.x;
    if (i >= n) return;
    float s = 0.f;
    #pragma unroll
    for (int z = 0; z < 8; ++z) s += in[(size_t)z * zstride + i];
    out[i] = s;
}

// fp32 -> bf16 (RNE), 4 elems/thread
__global__ __launch_bounds__(256)
void cast_rn(const float* __restrict__ in, unsigned short* __restrict__ out)
{
    const int i = blockIdx.x * 256 + threadIdx.x;
    float4 v = ((const float4*)in)[i];
    union { unsigned short u[4]; uint2 v2; } o;
    o.u[0] = f2bf(v.x); o.u[1] = f2bf(v.y); o.u[2] = f2bf(v.z); o.u[3] = f2bf(v.w);
    ((uint2*)out)[i] = o.v2;
}

// in[R][C] fp32 -> out[C][R] bf16, 32x32 LDS tiles
__global__ __launch_bounds__(256)
void transpose_cast(const float* __restrict__ in, unsigned short* __restrict__ out,
                    int R, int C)
{
    __shared__ float tile[32][33];
    const int tx = threadIdx.x & 31, ty = threadIdx.x >> 5;   // ty 0..7
    const int c0 = blockIdx.x * 32, r0 = blockIdx.y * 32;
    #pragma unroll
    for (int j = 0; j < 32; j += 8)
        tile[ty + j][tx] = in[(size_t)(r0 + ty + j) * C + c0 + tx];
    __syncthreads();
    #pragma unroll
    for (int j = 0; j < 32; j += 8)
        out[(size_t)(c0 + ty + j) * R + r0 + tx] = f2bf(tile[tx][ty + j]);
}

// ---------------------------------------------------------------------------
// Depthwise causal conv (D_CONV=4) + bias + SiLU over x_b (first half of xz)
// ---------------------------------------------------------------------------
__global__ __launch_bounds__(256)
void conv_silu(const float* __restrict__ xz, const float* __restrict__ conv_w,
               const float* __restrict__ conv_b, float* __restrict__ xc)
{
    const int idx = blockIdx.x * 256 + threadIdx.x;
    const int d = idx & (DINNER - 1);
    const int t = (idx >> 11) & (TLEN - 1);
    const int b = idx >> 21;

    const float* xb = xz + (size_t)b * TLEN * (2*DINNER) + d;
    float s = conv_b[d];
    const float4 w = *(const float4*)(conv_w + d * 4);
    const float wk[4] = {w.x, w.y, w.z, w.w};
    #pragma unroll
    for (int k = 0; k < 4; ++k) {
        const int tt = t + k - 3;
        if (tt >= 0) s = fmaf(xb[(size_t)tt * (2*DINNER)], wk[k], s);
    }
    xc[idx] = siluf(s);
}

// ---------------------------------------------------------------------------
// Scan pass A: per (b, chunk, d) — local scan from h0=0 and sum of delta
// ---------------------------------------------------------------------------
__global__ __launch_bounds__(256)
void scan1(const float* __restrict__ delta, const float* __restrict__ xc,
           const float* __restrict__ proj, const float* __restrict__ A_log,
           float* __restrict__ hloc, float* __restrict__ sumdel)
{
    const int idx = blockIdx.x * 256 + threadIdx.x;
    const int d = idx & (DINNER - 1);
    const int c = (idx >> 11) & (NCH - 1);
    const int b = idx >> 15;

    float Aa[DSTATE];
    #pragma unroll
    for (int s = 0; s < DSTATE; ++s) Aa[s] = -__expf(A_log[d * DSTATE + s]);

    float h[DSTATE];
    #pragma unroll
    for (int s = 0; s < DSTATE; ++s) h[s] = 0.f;
    float sd = 0.f;

    const int t0 = c * CH;
    const float* dptr = delta + ((size_t)(b * TLEN + t0)) * DINNER + d;
    const float* xptr = xc    + ((size_t)(b * TLEN + t0)) * DINNER + d;
    const float* pptr = proj  + ((size_t)(b * TLEN + t0)) * NPROJ;

    for (int t = 0; t < CH; ++t) {
        const float dl = dptr[(size_t)t * DINNER];
        const float xv = xptr[(size_t)t * DINNER];
        const float dx = dl * xv;
        sd += dl;
        #pragma unroll
        for (int s = 0; s < DSTATE; ++s) {
            const float ab = __expf(dl * Aa[s]);
            const float Bv = pptr[t * NPROJ + DTRANK + s];
            h[s] = fmaf(ab, h[s], dx * Bv);
        }
    }
    const size_t base = (((size_t)(b * DINNER + d)) * NCH + c) * DSTATE;
    #pragma unroll
    for (int s = 0; s < DSTATE; ++s) hloc[base + s] = h[s];
    sumdel[(size_t)(b * DINNER + d) * NCH + c] = sd;
}

// ---------------------------------------------------------------------------
// Scan pass B: per (b,d) — sequential combine of chunk states
// ---------------------------------------------------------------------------
__global__ __launch_bounds__(256)
void scan_combine(const float* __restrict__ hloc, const float* __restrict__ sumdel,
                  const float* __restrict__ A_log, float* __restrict__ hstart)
{
    const int idx = blockIdx.x * 256 + threadIdx.x;
    const int d = idx & (DINNER - 1);

    float Aa[DSTATE];
    #pragma unroll
    for (int s = 0; s < DSTATE; ++s) Aa[s] = -__expf(A_log[d * DSTATE + s]);

    float h[DSTATE];
    #pragma unroll
    for (int s = 0; s < DSTATE; ++s) h[s] = 0.f;

    const size_t base = (size_t)idx * NCH * DSTATE;
    for (int c = 0; c < NCH; ++c) {
        #pragma unroll
        for (int s = 0; s < DSTATE; ++s) hstart[base + c * DSTATE + s] = h[s];
        const float sd = sumdel[(size_t)idx * NCH + c];
        #pragma unroll
        for (int s = 0; s < DSTATE; ++s)
            h[s] = fmaf(__expf(Aa[s] * sd), h[s], hloc[base + c * DSTATE + s]);
    }
}

// ---------------------------------------------------------------------------
// Scan pass C: recompute with correct h0, produce y = (h.C + D*xc) * silu(z)
// ---------------------------------------------------------------------------
__global__ __launch_bounds__(256)
void scan2(const float* __restrict__ delta, const float* __restrict__ xc,
           const float* __restrict__ proj, const float* __restrict__ A_log,
           const float* __restrict__ D_param, const float* __restrict__ xz,
           const float* __restrict__ hstart, float* __restrict__ y)
{
    const int idx = blockIdx.x * 256 + threadIdx.x;
    const int d = idx & (DINNER - 1);
    const int c = (idx >> 11) & (NCH - 1);
    const int b = idx >> 15;

    float Aa[DSTATE];
    #pragma unroll
    for (int s = 0; s < DSTATE; ++s) Aa[s] = -__expf(A_log[d * DSTATE + s]);

    float h[DSTATE];
    const size_t hbase = (((size_t)(b * DINNER + d)) * NCH + c) * DSTATE;
    #pragma unroll
    for (int s = 0; s < DSTATE; ++s) h[s] = hstart[hbase + s];

    const float Dp = D_param[d];
    const int t0 = c * CH;
    const float* dptr = delta + ((size_t)(b * TLEN + t0)) * DINNER + d;
    const float* xptr = xc    + ((size_t)(b * TLEN + t0)) * DINNER + d;
    const float* pptr = proj  + ((size_t)(b * TLEN + t0)) * NPROJ;
    const float* zptr = xz + ((size_t)(b * TLEN + t0)) * (2*DINNER) + DINNER + d;
    float* yptr = y + ((size_t)(b * TLEN + t0)) * DINNER + d;

    for (int t = 0; t < CH; ++t) {
        const float dl = dptr[(size_t)t * DINNER];
        const float xv = xptr[(size_t)t * DINNER];
        const float dx = dl * xv;
        float yt = 0.f;
        #pragma unroll
        for (int s = 0; s < DSTATE; ++s) {
            const float ab = __expf(dl * Aa[s]);
            const float Bv = pptr[t * NPROJ + DTRANK + s];
            h[s] = fmaf(ab, h[s], dx * Bv);
            const float Cv = pptr[t * NPROJ + DTRANK + DSTATE + s];
            yt = fmaf(h[s], Cv, yt);
        }
        yt = fmaf(Dp, xv, yt);
        const float z = zptr[(size_t)t * (2*DINNER)];
        yptr[(size_t)t * DINNER] = yt * siluf(z);
    }
}

// ---------------------------------------------------------------------------
extern "C" void kernel_launch(void* const* d_in, const int* in_sizes, int n_in,
                              void* d_out, int out_size, void* d_ws, size_t ws_size,
                              hipStream_t stream)
{
    const float* x      = (const float*)d_in[0];
    const float* W_in   = (const float*)d_in[1];
    const float* conv_w = (const float*)d_in[2];
    const float* conv_b = (const float*)d_in[3];
    const float* W_xproj= (const float*)d_in[4];
    const float* W_dt   = (const float*)d_in[5];
    const float* b_dt   = (const float*)d_in[6];
    const float* A_log  = (const float*)d_in[7];
    const float* D_param= (const float*)d_in[8];
    const float* W_out  = (const float*)d_in[9];
    float* out = (float*)d_out;

    // ---- workspace layout (floats). Total 26,476,544 fl = 101 MB.
    float* ws = (float*)d_ws;
    float* xz     = ws;                       // 8,388,608
    float* xc     = xz     + 8388608;         // 4,194,304
    float* proj   = xc     + 4194304;         //   196,608
    float* delta  = proj   + 196608;          // 4,194,304
    float* yb     = delta  + 4194304;         // 4,194,304
    float* hloc   = yb     + 4194304;         // 1,048,576   (region S start)
    float* sumdel = hloc   + 1048576;         //    65,536
    float* hstart = sumdel + 65536;           // 1,048,576
    float* projp  = hloc;                     // alias: 8*196,608 fl, dead before scan1
    float* T      = hstart + 1048576;         // region T: 3,145,728 fl, two phases
    unsigned short* x_bf  = (unsigned short*)T;               // 2,097,152 sh
    unsigned short* wt_in = (unsigned short*)(T + 1048576);   // 4,194,304 sh
    unsigned short* yb_bf = (unsigned short*)T;               // 4,194,304 sh (phase 2)
    unsigned short* wt_out= (unsigned short*)(T + 2097152);   // 2,097,152 sh (phase 2)

    dim3 blk(256);

    // 1. bf16 casts for GEMM1, then xz = x @ W_in   (M=2048, N=4096, K=1024)
    cast_rn<<<(BATCH*TLEN*DMODEL/4)/256, blk, 0, stream>>>(x, x_bf);
    transpose_cast<<<dim3(2*DINNER/32, DMODEL/32), blk, 0, stream>>>(W_in, wt_in, DMODEL, 2*DINNER);
    gemm_bf16<4><<<dim3(2*DINNER/128, 2048/128), blk, 0, stream>>>(x_bf, wt_in, xz, 2*DINNER, DMODEL);

    // 2. xc = silu(conv(x_b))
    conv_silu<<<(BATCH*TLEN*DINNER)/256, blk, 0, stream>>>(xz, conv_w, conv_b, xc);

    // 3. proj = xc @ W_xproj  (M=2048, N=96, K=2048) — split-K x8, fp32
    gemm_f32<0><<<dim3(2, 2048/64, 8), blk, 0, stream>>>(
        xc, DINNER, W_xproj, NPROJ, projp, NPROJ, NPROJ, DINNER/8, nullptr, 196608);
    reduce8<<<(196608 + 255)/256, blk, 0, stream>>>(projp, proj, 196608, 196608);

    // 4. delta = softplus(proj[:, :64] @ W_dt + b_dt)   (M=2048, N=2048, K=64) fp32
    gemm_f32<1><<<dim3(2048/64, 2048/64), blk, 0, stream>>>(
        proj, NPROJ, W_dt, DINNER, delta, DINNER, DINNER, DTRANK, b_dt, 0);

    // 5-7. chunked scan
    scan1<<<65536/256, blk, 0, stream>>>(delta, xc, proj, A_log, hloc, sumdel);
    scan_combine<<<4096/256, blk, 0, stream>>>(hloc, sumdel, A_log, hstart);
    scan2<<<65536/256, blk, 0, stream>>>(delta, xc, proj, A_log, D_param, xz, hstart, yb);

    // 8. out = yb @ W_out   (M=2048, N=1024, K=2048) bf16 MFMA, BN=64 -> 256 blocks
    cast_rn<<<(BATCH*TLEN*DINNER/4)/256, blk, 0, stream>>>(yb, yb_bf);
    transpose_cast<<<dim3(DMODEL/32, DINNER/32), blk, 0, stream>>>(W_out, wt_out, DINNER, DMODEL);
    gemm_bf16<2><<<dim3(DMODEL/64, 2048/128), blk, 0, stream>>>(yb_bf, wt_out, out, DMODEL, DINNER);
}

// Round 3
// 289.706 us; speedup vs baseline: 2.5432x; 1.2038x over previous
//
#include <hip/hip_runtime.h>
#include <math.h>

#define BATCH   2
#define TLEN    1024
#define DMODEL  1024
#define DINNER  2048
#define DSTATE  16
#define DTRANK  64
#define NPROJ   (DTRANK + 2*DSTATE)   // 96
#define CH      16
#define NCH     (TLEN / CH)           // 64

typedef __attribute__((ext_vector_type(8))) short short8;
typedef __attribute__((ext_vector_type(4))) float f32x4;

__device__ __forceinline__ float siluf(float u) {
    return u / (1.0f + __expf(-u));
}
__device__ __forceinline__ float softplusf(float x) {
    return (x > 20.0f) ? x : log1pf(__expf(x));
}
__device__ __forceinline__ unsigned short f2bf(float f) {
    union { float f; unsigned u; } v; v.f = f;
    unsigned r = v.u + 0x7FFF + ((v.u >> 16) & 1);   // round-to-nearest-even
    return (unsigned short)(r >> 16);
}

#define GLOAD_LDS16(g, l) \
  __builtin_amdgcn_global_load_lds( \
     (const __attribute__((address_space(1))) unsigned int*)(g), \
     (__attribute__((address_space(3))) unsigned int*)(l), 16, 0, 0)

// ---------------------------------------------------------------------------
// bf16 MFMA GEMM: C[M, N] fp32 = A[M,K]bf16 @ BT[N,K]bf16^T
// BM=128, BN=NFRAG*32 (4->128, 2->64), BK=32, 256 threads = 4 waves (2x2).
// ---------------------------------------------------------------------------
template<int NFRAG>
__global__ __launch_bounds__(256)
void gemm_bf16(const unsigned short* __restrict__ A,
               const unsigned short* __restrict__ BT,
               float* __restrict__ C, int ldc, int K)
{
    constexpr int BN = NFRAG * 32;
    __shared__ unsigned short As[128 * 32];
    __shared__ unsigned short Bs[BN * 32];

    const int tid  = threadIdx.x;
    const int wid  = tid >> 6;
    const int lane = tid & 63;
    const int brow = blockIdx.y * 128;
    const int bcol = blockIdx.x * BN;
    const int wr = (wid >> 1) * 64;
    const int wc = (wid & 1) * (NFRAG * 16);
    const int lrow = lane & 15;
    const int lk   = (lane >> 4) * 8;

    f32x4 acc[4][NFRAG] = {};

    for (int k0 = 0; k0 < K; k0 += 32) {
        #pragma unroll
        for (int it = 0; it < 2; ++it) {
            const int c = it * 256 + tid;
            const unsigned short* g = A + (size_t)(brow + (c >> 2)) * K + k0 + (c & 3) * 8;
            GLOAD_LDS16(g, As + (size_t)(it * 256 + wid * 64) * 8);
        }
        #pragma unroll
        for (int it = 0; it < BN / 64; ++it) {
            const int c = it * 256 + tid;
            const unsigned short* g = BT + (size_t)(bcol + (c >> 2)) * K + k0 + (c & 3) * 8;
            GLOAD_LDS16(g, Bs + (size_t)(it * 256 + wid * 64) * 8);
        }
        __syncthreads();

        short8 af[4], bfr[NFRAG];
        #pragma unroll
        for (int m = 0; m < 4; ++m)
            af[m] = *(const short8*)(As + (size_t)(wr + m * 16 + lrow) * 32 + lk);
        #pragma unroll
        for (int n = 0; n < NFRAG; ++n)
            bfr[n] = *(const short8*)(Bs + (size_t)(wc + n * 16 + lrow) * 32 + lk);

        #pragma unroll
        for (int m = 0; m < 4; ++m)
            #pragma unroll
            for (int n = 0; n < NFRAG; ++n)
                acc[m][n] = __builtin_amdgcn_mfma_f32_16x16x32_bf16(af[m], bfr[n], acc[m][n], 0, 0, 0);
        __syncthreads();
    }

    const int crow = (lane >> 4) * 4;
    #pragma unroll
    for (int m = 0; m < 4; ++m)
        #pragma unroll
        for (int n = 0; n < NFRAG; ++n) {
            float* cp = C + (size_t)(brow + wr + m * 16 + crow) * ldc + bcol + wc + n * 16 + lrow;
            #pragma unroll
            for (int r = 0; r < 4; ++r)
                cp[(size_t)r * ldc] = acc[m][n][r];
        }
}

// ---------------------------------------------------------------------------
// fp32 tiled GEMM with split-K via gridDim.z. EPI=1: softplus(C + bias[col])
// ---------------------------------------------------------------------------
template<int EPI>
__global__ __launch_bounds__(256)
void gemm_f32(const float* __restrict__ A, int lda,
              const float* __restrict__ B, int ldb,
              float* __restrict__ C, int ldc,
              int N, int kchunk,
              const float* __restrict__ bias, size_t zstride)
{
    __shared__ float As[16][64 + 4];
    __shared__ float Bs[16][64 + 4];
    const int tid  = threadIdx.x;
    const int brow = blockIdx.y * 64;
    const int bcol = blockIdx.x * 64;
    const int kbeg = blockIdx.z * kchunk;
    C += (size_t)blockIdx.z * zstride;
    const int tr = ((tid >> 4) & 15) << 2;
    const int tc = (tid & 15) << 2;
    const int ar = tid >> 2;
    const int ac = (tid & 3) << 2;
    const int br = tid >> 4;
    const int bc = (tid & 15) << 2;

    float acc[4][4] = {{0.f,0.f,0.f,0.f},{0.f,0.f,0.f,0.f},
                       {0.f,0.f,0.f,0.f},{0.f,0.f,0.f,0.f}};

    for (int k0 = kbeg; k0 < kbeg + kchunk; k0 += 16) {
        float4 av = *(const float4*)(A + (size_t)(brow + ar) * lda + k0 + ac);
        As[ac+0][ar] = av.x; As[ac+1][ar] = av.y;
        As[ac+2][ar] = av.z; As[ac+3][ar] = av.w;

        float4 bv = make_float4(0.f, 0.f, 0.f, 0.f);
        if (bcol + bc < N)
            bv = *(const float4*)(B + (size_t)(k0 + br) * ldb + bcol + bc);
        *(float4*)&Bs[br][bc] = bv;

        __syncthreads();
        #pragma unroll
        for (int k = 0; k < 16; ++k) {
            float4 a4 = *(const float4*)&As[k][tr];
            float4 b4 = *(const float4*)&Bs[k][tc];
            float am[4] = {a4.x, a4.y, a4.z, a4.w};
            float bn[4] = {b4.x, b4.y, b4.z, b4.w};
            #pragma unroll
            for (int m = 0; m < 4; ++m)
                #pragma unroll
                for (int n = 0; n < 4; ++n)
                    acc[m][n] = fmaf(am[m], bn[n], acc[m][n]);
        }
        __syncthreads();
    }

    #pragma unroll
    for (int m = 0; m < 4; ++m) {
        const int gr = brow + tr + m;
        #pragma unroll
        for (int n = 0; n < 4; ++n) {
            const int gc = bcol + tc + n;
            if (gc < N) {
                float v = acc[m][n];
                if (EPI == 1) v = softplusf(v + bias[gc]);
                C[(size_t)gr * ldc + gc] = v;
            }
        }
    }
}

__global__ __launch_bounds__(256)
void reduce8(const float* __restrict__ in, float* __restrict__ out, int n, size_t zstride)
{
    const int i = blockIdx.x * 256 + threadIdx.x;
    if (i >= n) return;
    float s = 0.f;
    #pragma unroll
    for (int z = 0; z < 8; ++z) s += in[(size_t)z * zstride + i];
    out[i] = s;
}

__global__ __launch_bounds__(256)
void cast_rn(const float* __restrict__ in, unsigned short* __restrict__ out)
{
    const int i = blockIdx.x * 256 + threadIdx.x;
    float4 v = ((const float4*)in)[i];
    union { unsigned short u[4]; uint2 v2; } o;
    o.u[0] = f2bf(v.x); o.u[1] = f2bf(v.y); o.u[2] = f2bf(v.z); o.u[3] = f2bf(v.w);
    ((uint2*)out)[i] = o.v2;
}

__global__ __launch_bounds__(256)
void transpose_cast(const float* __restrict__ in, unsigned short* __restrict__ out,
                    int R, int C)
{
    __shared__ float tile[32][33];
    const int tx = threadIdx.x & 31, ty = threadIdx.x >> 5;
    const int c0 = blockIdx.x * 32, r0 = blockIdx.y * 32;
    #pragma unroll
    for (int j = 0; j < 32; j += 8)
        tile[ty + j][tx] = in[(size_t)(r0 + ty + j) * C + c0 + tx];
    __syncthreads();
    #pragma unroll
    for (int j = 0; j < 32; j += 8)
        out[(size_t)(c0 + ty + j) * R + r0 + tx] = f2bf(tile[tx][ty + j]);
}

// ---------------------------------------------------------------------------
__global__ __launch_bounds__(256)
void conv_silu(const float* __restrict__ xz, const float* __restrict__ conv_w,
               const float* __restrict__ conv_b, float* __restrict__ xc)
{
    const int idx = blockIdx.x * 256 + threadIdx.x;
    const int d = idx & (DINNER - 1);
    const int t = (idx >> 11) & (TLEN - 1);
    const int b = idx >> 21;

    const float* xb = xz + (size_t)b * TLEN * (2*DINNER) + d;
    float s = conv_b[d];
    const float4 w = *(const float4*)(conv_w + d * 4);
    const float wk[4] = {w.x, w.y, w.z, w.w};
    #pragma unroll
    for (int k = 0; k < 4; ++k) {
        const int tt = t + k - 3;
        if (tt >= 0) s = fmaf(xb[(size_t)tt * (2*DINNER)], wk[k], s);
    }
    xc[idx] = siluf(s);
}

// ---------------------------------------------------------------------------
// Scan pass A: per (b, chunk, d) — local scan from h0=0 (CH=16) + sum of delta
// hloc layout: [b*DINNER+d][c][s]  (64B contiguous per (bd,c))
// ---------------------------------------------------------------------------
__global__ __launch_bounds__(256)
void scan1(const float* __restrict__ delta, const float* __restrict__ xc,
           const float* __restrict__ proj, const float* __restrict__ A_log,
           float* __restrict__ hloc, float* __restrict__ sumdel)
{
    const int idx = blockIdx.x * 256 + threadIdx.x;   // B*NCH*DINNER = 262144
    const int d = idx & (DINNER - 1);
    const int c = (idx >> 11) & (NCH - 1);
    const int b = idx >> 17;

    float Aa[DSTATE];
    #pragma unroll
    for (int s = 0; s < DSTATE; ++s) Aa[s] = -__expf(A_log[d * DSTATE + s]);

    float h[DSTATE];
    #pragma unroll
    for (int s = 0; s < DSTATE; ++s) h[s] = 0.f;
    float sd = 0.f;

    const int t0 = c * CH;
    const float* dptr = delta + ((size_t)(b * TLEN + t0)) * DINNER + d;
    const float* xptr = xc    + ((size_t)(b * TLEN + t0)) * DINNER + d;
    const float* pptr = proj  + ((size_t)(b * TLEN + t0)) * NPROJ;

    for (int t = 0; t < CH; ++t) {
        const float dl = dptr[(size_t)t * DINNER];
        const float xv = xptr[(size_t)t * DINNER];
        const float dx = dl * xv;
        sd += dl;
        #pragma unroll
        for (int s = 0; s < DSTATE; ++s) {
            const float ab = __expf(dl * Aa[s]);
            const float Bv = pptr[t * NPROJ + DTRANK + s];
            h[s] = fmaf(ab, h[s], dx * Bv);
        }
    }
    const size_t base = (((size_t)(b * DINNER + d)) * NCH + c) * DSTATE;
    float4* hp = (float4*)(hloc + base);
    hp[0] = make_float4(h[0],  h[1],  h[2],  h[3]);
    hp[1] = make_float4(h[4],  h[5],  h[6],  h[7]);
    hp[2] = make_float4(h[8],  h[9],  h[10], h[11]);
    hp[3] = make_float4(h[12], h[13], h[14], h[15]);
    sumdel[(size_t)(b * DINNER + d) * NCH + c] = sd;
}

// ---------------------------------------------------------------------------
// Scan pass B: wave-parallel affine scan over NCH=64 chunks (lanes = chunks).
// One block per (b,d); wave w handles states 4w..4w+3; Hillis-Steele, 6 steps.
// ---------------------------------------------------------------------------
__global__ __launch_bounds__(256)
void scan_combine(const float* __restrict__ hloc, const float* __restrict__ sumdel,
                  const float* __restrict__ A_log, float* __restrict__ hstart)
{
    __shared__ float hl[64 * 17];
    __shared__ float hs[64 * 17];
    const int bd   = blockIdx.x;          // b*DINNER+d, 0..4095
    const int d    = bd & (DINNER - 1);
    const int tid  = threadIdx.x;
    const int lane = tid & 63;            // chunk index
    const int w    = tid >> 6;            // wave 0..3

    const size_t gbase = (size_t)bd * NCH * DSTATE;   // 1024 floats
    {
        const float4 v = ((const float4*)(hloc + gbase))[tid];
        const int c = tid >> 2, s0 = (tid & 3) * 4;
        hl[c*17 + s0+0] = v.x; hl[c*17 + s0+1] = v.y;
        hl[c*17 + s0+2] = v.z; hl[c*17 + s0+3] = v.w;
    }
    const float sd = sumdel[(size_t)bd * NCH + lane];
    __syncthreads();

    #pragma unroll
    for (int q = 0; q < 4; ++q) {
        const int s = w * 4 + q;
        const float Aa = -__expf(A_log[d * DSTATE + s]);
        float A  = __expf(Aa * sd);       // chunk A-product
        float Bv = hl[lane*17 + s];       // chunk local end-state
        #pragma unroll
        for (int off = 1; off < 64; off <<= 1) {
            float Ap = __shfl_up(A, off);
            float Bp = __shfl_up(Bv, off);
            if (lane >= off) { Bv = fmaf(A, Bp, Bv); A *= Ap; }
        }
        float hsv = __shfl_up(Bv, 1);     // exclusive: hstart[c] = H_end(c-1)
        if (lane == 0) hsv = 0.f;
        hs[lane*17 + s] = hsv;
    }
    __syncthreads();
    {
        const int c = tid >> 2, s0 = (tid & 3) * 4;
        float4 v = make_float4(hs[c*17 + s0+0], hs[c*17 + s0+1],
                               hs[c*17 + s0+2], hs[c*17 + s0+3]);
        ((float4*)(hstart + gbase))[tid] = v;
    }
}

// ---------------------------------------------------------------------------
// Scan pass C: recompute with correct h0; y = (h.C + D*xc)*silu(z), bf16 out
// ---------------------------------------------------------------------------
__global__ __launch_bounds__(256)
void scan2(const float* __restrict__ delta, const float* __restrict__ xc,
           const float* __restrict__ proj, const float* __restrict__ A_log,
           const float* __restrict__ D_param, const float* __restrict__ xz,
           const float* __restrict__ hstart, unsigned short* __restrict__ y)
{
    const int idx = blockIdx.x * 256 + threadIdx.x;
    const int d = idx & (DINNER - 1);
    const int c = (idx >> 11) & (NCH - 1);
    const int b = idx >> 17;

    float Aa[DSTATE];
    #pragma unroll
    for (int s = 0; s < DSTATE; ++s) Aa[s] = -__expf(A_log[d * DSTATE + s]);

    float h[DSTATE];
    const size_t hbase = (((size_t)(b * DINNER + d)) * NCH + c) * DSTATE;
    {
        const float4* hp = (const float4*)(hstart + hbase);
        float4 v0 = hp[0], v1 = hp[1], v2 = hp[2], v3 = hp[3];
        h[0]=v0.x; h[1]=v0.y; h[2]=v0.z; h[3]=v0.w;
        h[4]=v1.x; h[5]=v1.y; h[6]=v1.z; h[7]=v1.w;
        h[8]=v2.x; h[9]=v2.y; h[10]=v2.z; h[11]=v2.w;
        h[12]=v3.x; h[13]=v3.y; h[14]=v3.z; h[15]=v3.w;
    }

    const float Dp = D_param[d];
    const int t0 = c * CH;
    const float* dptr = delta + ((size_t)(b * TLEN + t0)) * DINNER + d;
    const float* xptr = xc    + ((size_t)(b * TLEN + t0)) * DINNER + d;
    const float* pptr = proj  + ((size_t)(b * TLEN + t0)) * NPROJ;
    const float* zptr = xz + ((size_t)(b * TLEN + t0)) * (2*DINNER) + DINNER + d;
    unsigned short* yptr = y + ((size_t)(b * TLEN + t0)) * DINNER + d;

    for (int t = 0; t < CH; ++t) {
        const float dl = dptr[(size_t)t * DINNER];
        const float xv = xptr[(size_t)t * DINNER];
        const float dx = dl * xv;
        float yt = 0.f;
        #pragma unroll
        for (int s = 0; s < DSTATE; ++s) {
            const float ab = __expf(dl * Aa[s]);
            const float Bv = pptr[t * NPROJ + DTRANK + s];
            h[s] = fmaf(ab, h[s], dx * Bv);
            const float Cv = pptr[t * NPROJ + DTRANK + DSTATE + s];
            yt = fmaf(h[s], Cv, yt);
        }
        yt = fmaf(Dp, xv, yt);
        const float z = zptr[(size_t)t * (2*DINNER)];
        yptr[(size_t)t * DINNER] = f2bf(yt * siluf(z));
    }
}

// ---------------------------------------------------------------------------
extern "C" void kernel_launch(void* const* d_in, const int* in_sizes, int n_in,
                              void* d_out, int out_size, void* d_ws, size_t ws_size,
                              hipStream_t stream)
{
    const float* x      = (const float*)d_in[0];
    const float* W_in   = (const float*)d_in[1];
    const float* conv_w = (const float*)d_in[2];
    const float* conv_b = (const float*)d_in[3];
    const float* W_xproj= (const float*)d_in[4];
    const float* W_dt   = (const float*)d_in[5];
    const float* b_dt   = (const float*)d_in[6];
    const float* A_log  = (const float*)d_in[7];
    const float* D_param= (const float*)d_in[8];
    const float* W_out  = (const float*)d_in[9];
    float* out = (float*)d_out;

    // ---- workspace (floats): 25,624,576 fl = 97.8 MB
    float* ws = (float*)d_ws;
    float* xz     = ws;                       // 8,388,608
    float* xc     = xz     + 8388608;         // 4,194,304
    float* proj   = xc     + 4194304;         //   196,608
    float* delta  = proj   + 196608;          // 4,194,304
    float* hloc   = delta  + 4194304;         // 4,194,304
    float* sumdel = hloc   + 4194304;         //   262,144
    float* hstart = sumdel + 262144;          // 4,194,304
    // aliases (lifetimes disjoint, single stream):
    float* projp  = hloc;                              // steps 3 only
    unsigned short* x_bf  = (unsigned short*)hstart;               // pre-scan
    unsigned short* wt_in = (unsigned short*)(hstart + 1048576);   // pre-scan
    unsigned short* yb_bf = (unsigned short*)hloc;                 // post-combine
    unsigned short* wt_out= (unsigned short*)(hloc + 2097152);     // post-combine

    dim3 blk(256);

    // 1. xz = x @ W_in  (bf16 MFMA; M=2048, N=4096, K=1024)
    cast_rn<<<(BATCH*TLEN*DMODEL/4)/256, blk, 0, stream>>>(x, x_bf);
    transpose_cast<<<dim3(2*DINNER/32, DMODEL/32), blk, 0, stream>>>(W_in, wt_in, DMODEL, 2*DINNER);
    gemm_bf16<4><<<dim3(2*DINNER/128, 2048/128), blk, 0, stream>>>(x_bf, wt_in, xz, 2*DINNER, DMODEL);

    // 2. xc = silu(conv(x_b))
    conv_silu<<<(BATCH*TLEN*DINNER)/256, blk, 0, stream>>>(xz, conv_w, conv_b, xc);

    // 3. proj = xc @ W_xproj  (M=2048, N=96, K=2048) — split-K x8, fp32
    gemm_f32<0><<<dim3(2, 2048/64, 8), blk, 0, stream>>>(
        xc, DINNER, W_xproj, NPROJ, projp, NPROJ, NPROJ, DINNER/8, nullptr, 196608);
    reduce8<<<(196608 + 255)/256, blk, 0, stream>>>(projp, proj, 196608, 196608);

    // 4. delta = softplus(proj[:, :64] @ W_dt + b_dt)  (M=2048, N=2048, K=64)
    gemm_f32<1><<<dim3(2048/64, 2048/64), blk, 0, stream>>>(
        proj, NPROJ, W_dt, DINNER, delta, DINNER, DINNER, DTRANK, b_dt, 0);

    // 5-7. chunked scan (CH=16, NCH=64)
    scan1<<<(BATCH*NCH*DINNER)/256, blk, 0, stream>>>(delta, xc, proj, A_log, hloc, sumdel);
    scan_combine<<<BATCH*DINNER, blk, 0, stream>>>(hloc, sumdel, A_log, hstart);
    transpose_cast<<<dim3(DMODEL/32, DINNER/32), blk, 0, stream>>>(W_out, wt_out, DINNER, DMODEL);
    scan2<<<(BATCH*NCH*DINNER)/256, blk, 0, stream>>>(delta, xc, proj, A_log, D_param, xz, hstart, yb_bf);

    // 8. out = yb @ W_out  (M=2048, N=1024, K=2048) bf16 MFMA
    gemm_bf16<2><<<dim3(DMODEL/64, 2048/128), blk, 0, stream>>>(yb_bf, wt_out, out, DMODEL, DINNER);
}